// Round 5
// baseline (1328.228 us; speedup 1.0000x reference)
//
#include <hip/hip_runtime.h>
#include <hip/hip_fp16.h>

// Unidir_LSTM: h_t = sig(o)*tanh(sig(i)*tanh(g)); f-gate dead (cell carry always 0).
// R10: R5/R7/R9 — three different handoff protocols, all ~4.5-5.2us/step. The step
//   time is protocol-INSENSITIVE; compute+latency models give ~1.2-1.8us. The one
//   invariant: ~128 waves/group hammer the flag line(s) every poll round (R9: 128
//   waves x 1 line; R7: each wave reads all 32 lines -> same per-line rate). Theory:
//   same-line MALL request serialization (~1 req/5cy + 32 RMWs) IS the missing
//   ~2.5us. MfmaUtil/VALUBusy ~11-13% agree: waves idle ~70% of each step.
// Fix (contention, not protocol):
//   - 4 counter lines per (bg,t), aligned to K-quarters: producer n signals line
//     n>>3; consumer wave w polls ONLY line w (its 8 producers = exactly the
//     h-cols it consumes). 32 pollers/line (was 128), s_sleep(2) backoff, and
//     early quarters start h-MFMAs while the straggler quarter settles.
//   - X-MFMAs hoisted BEFORE the poll (depend only on prefetched X + reg weights)
//     -> off the serial path.
//   - Keep R9-proven: agent-scope atomics (hang-proof), parity gbuf, 2 barriers,
//     per-wave vmcnt(0) drain before the block-wide release fetch_add.
// Predict: if contention theory right, recur 1152 -> ~600-750us (step ~2.3-2.8us),
//   MfmaUtil ~17-20%; if recur only ~1050-1100 -> strong null => fabric visibility
//   latency floor, not contention. FETCH/WRITE ~unchanged, conflicts 0.

typedef __fp16 f16x8 __attribute__((ext_vector_type(8)));
typedef __fp16 f16x4 __attribute__((ext_vector_type(4)));
typedef float  f32x4 __attribute__((ext_vector_type(4)));

#define MFMA16(a, b, c) __builtin_amdgcn_mfma_f32_16x16x32_f16(a, b, c, 0, 0, 0)

__device__ __forceinline__ float sigmoid_f(float x) {
  return 1.f / (1.f + __expf(-x));
}
__device__ __forceinline__ float tanh_f(float x) {
  x = fminf(fmaxf(x, -15.f), 15.f);
  float e = __expf(2.f * x);
  return (e - 1.f) / (e + 1.f);
}

static constexpr int SS = 256;

// ---------------- prep: pack W_ih/W_hh rows {i,g,o} to fp16, bias3 = b_ih+b_hh ----
__global__ void prep_kernel(const float* __restrict__ W_ih, const float* __restrict__ W_hh,
                            const float* __restrict__ b_ih, const float* __restrict__ b_hh,
                            __fp16* __restrict__ Wi3, __fp16* __restrict__ Wh3,
                            float* __restrict__ bias3) {
  int j3 = blockIdx.x;                 // 0..3071 packed row
  int g = j3 >> 10, j = j3 & 1023;
  int orig = (g == 0 ? 0 : (g == 1 ? 2048 : 3072)) + j;  // i,g,o rows of 4H
  int tid = threadIdx.x;
  {
    float4 v = *(const float4*)(W_hh + (size_t)orig * 1024 + tid * 4);
    f16x4 o = {(__fp16)v.x, (__fp16)v.y, (__fp16)v.z, (__fp16)v.w};
    *(f16x4*)(Wh3 + (size_t)j3 * 1024 + tid * 4) = o;
  }
  if (tid < 128) {
    float4 v = *(const float4*)(W_ih + (size_t)orig * 512 + tid * 4);
    f16x4 o = {(__fp16)v.x, (__fp16)v.y, (__fp16)v.z, (__fp16)v.w};
    *(f16x4*)(Wi3 + (size_t)j3 * 512 + tid * 4) = o;
  }
  if (tid == 0) bias3[j3] = b_ih[orig] + b_hh[orig];
}

// ---------------- gather: X[t*128+b][e] = fp16(embed[tok[b][t]][e]) ----------------
__global__ void gather_kernel(const int* __restrict__ tok, const float* __restrict__ emb,
                              __fp16* __restrict__ X) {
  int m = blockIdx.x;                  // 0..32767 = t*128 + b
  int t = m >> 7, b = m & 127;
  int tk = tok[b * SS + t];            // inputs is [B][S]
  int e0 = threadIdx.x * 8;
  const float* src = emb + (size_t)tk * 512 + e0;
  float4 v0 = *(const float4*)src;
  float4 v1 = *(const float4*)(src + 4);
  f16x8 o;
  o[0] = (__fp16)v0.x; o[1] = (__fp16)v0.y; o[2] = (__fp16)v0.z; o[3] = (__fp16)v0.w;
  o[4] = (__fp16)v1.x; o[5] = (__fp16)v1.y; o[6] = (__fp16)v1.z; o[7] = (__fp16)v1.w;
  *(f16x8*)(X + (size_t)m * 512 + e0) = o;
}

// ---------------- recurrence: persistent, fused input GEMM, quarter-wise handoff --
// 256 blocks = (bg 0..7: 16 batch rows, XCD-pinned via bid&7) x (n 0..31: 32
// h-cols). 4 waves = 4 disjoint K-quarters. Per step, per wave:
//   X A-frags (prefetched at iter top) -> 24 X-MFMAs BEFORE the poll (h-independent)
//   poll line kq of (bg,t): the 8 producers of exactly this wave's h-columns
//   h A-frags global->VGPR, 48 h-MFMAs, 4-way K-reduce via parity gbuf (1 barrier)
//   epilogue on all 4 waves, per-wave vmcnt(0), release barrier, tid0 agent
//   fetch_add on line (n>>3) of (bg,t+1).
__global__ __launch_bounds__(256, 1) void recur_kernel(const __fp16* __restrict__ Wh3,
                                                       const __fp16* __restrict__ Wi3,
                                                       const __fp16* __restrict__ X,
                                                       const float* __restrict__ bias3,
                                                       __fp16* __restrict__ hbuf,
                                                       int* __restrict__ cnt,
                                                       float* __restrict__ out) {
  const int bid = blockIdx.x;
  const int bg = bid & 7, n = bid >> 3;   // XCD-local batch groups
  const int b0 = bg * 16, j0 = n * 32;
  const int tid = threadIdx.x, wid = tid >> 6, lane = tid & 63;
  const int l15 = lane & 15, quad = lane >> 4;
  const int kq = wid;                     // this wave's K-quarter
  const int ct_e = wid & 1, rh = wid >> 1;  // epilogue ownership: col-tile, row-half

  // parity-double-buffered; stride 20 floats -> 2-way banks (free, m136)
  __shared__ float gbuf[2][4][3][2][16][20];

  // persistent B fragments (col = j0 + ct*16 + l15, k = quarter + kk*32 + quad*8)
  f16x8 wh[3][2][8];
  f16x8 wi[3][2][4];
#pragma unroll
  for (int g = 0; g < 3; ++g)
#pragma unroll
    for (int ct = 0; ct < 2; ++ct) {
      const __fp16* wr = Wh3 + (size_t)(g * 1024 + j0 + ct * 16 + l15) * 1024 + kq * 256 + quad * 8;
#pragma unroll
      for (int kk = 0; kk < 8; ++kk) wh[g][ct][kk] = *(const f16x8*)(wr + kk * 32);
      const __fp16* wr2 = Wi3 + (size_t)(g * 1024 + j0 + ct * 16 + l15) * 512 + kq * 128 + quad * 8;
#pragma unroll
      for (int kk = 0; kk < 4; ++kk) wi[g][ct][kk] = *(const f16x8*)(wr2 + kk * 32);
    }

  float bs[3];
#pragma unroll
  for (int g = 0; g < 3; ++g) bs[g] = bias3[g * 1024 + j0 + ct_e * 16 + l15];

  const __fp16* xrow = X + (size_t)(b0 + l15) * 512 + kq * 128 + quad * 8;
  const __fp16* hrow = hbuf + (size_t)(b0 + l15) * 1024 + kq * 256 + quad * 8;
  // counter layout: [bg][t][line 0..3], 64B per line
  int* cbase = cnt + bg * 16384;
  const int* mypoll0 = cbase + kq * 16;            // + t*64
  int* myflag0 = cbase + (n >> 3) * 16;            // + (t+1)*64

  for (int t = 0; t < SS; ++t) {
    // (a) X A-frags + X-MFMAs: fully h-independent -> run BEFORE the poll. This
    //     work (and any X-load stall) overlaps the producers' tail, off the chain.
    f16x8 xa[4];
    {
      const __fp16* xp = xrow + (size_t)t * 65536;
#pragma unroll
      for (int kk = 0; kk < 4; ++kk) xa[kk] = *(const f16x8*)(xp + kk * 32);
    }
    f32x4 acc[3][2];
#pragma unroll
    for (int g = 0; g < 3; ++g)
#pragma unroll
      for (int ct = 0; ct < 2; ++ct) {
        f32x4 z = {0.f, 0.f, 0.f, 0.f};
        acc[g][ct] = z;
      }
#pragma unroll
    for (int kk = 0; kk < 4; ++kk)
#pragma unroll
      for (int g = 0; g < 3; ++g)
#pragma unroll
        for (int ct = 0; ct < 2; ++ct)
          acc[g][ct] = MFMA16(xa[kk], wi[g][ct][kk], acc[g][ct]);
    // (b) poll ONLY this wave's K-quarter line: its 8 producers cover exactly the
    //     h-columns this wave consumes. 32 pollers/line (was 128), same-address
    //     broadcast load, s_sleep backoff. Agent scope = device coherence point
    //     (hang-proof, R7/R9-proven).
    if (t > 0) {
      const int* pollp = mypoll0 + t * 64;
      for (;;) {
        int v = __hip_atomic_load(pollp, __ATOMIC_RELAXED, __HIP_MEMORY_SCOPE_AGENT);
        if (v >= 8) break;
        __builtin_amdgcn_s_sleep(2);
      }
      asm volatile("" ::: "memory");
    }
    // (c) h A-frags global->VGPR (XCD-L2/MALL), then 48 h-MFMAs
    f16x8 ha[8];
    {
      const __fp16* hp = hrow + (size_t)t * 131072;
#pragma unroll
      for (int kk = 0; kk < 8; ++kk) ha[kk] = *(const f16x8*)(hp + kk * 32);
    }
#pragma unroll
    for (int kk = 0; kk < 8; ++kk)
#pragma unroll
      for (int g = 0; g < 3; ++g)
#pragma unroll
        for (int ct = 0; ct < 2; ++ct)
          acc[g][ct] = MFMA16(ha[kk], wh[g][ct][kk], acc[g][ct]);
    // (d) 4-way K reduction via parity gbuf (single barrier)
    const int tp = t & 1;
#pragma unroll
    for (int g = 0; g < 3; ++g)
#pragma unroll
      for (int ct = 0; ct < 2; ++ct)
#pragma unroll
        for (int r = 0; r < 4; ++r)
          gbuf[tp][kq][g][ct][quad * 4 + r][l15] = acc[g][ct][r];
    __syncthreads();
    float sum[3][2];
#pragma unroll
    for (int g = 0; g < 3; ++g)
#pragma unroll
      for (int rr = 0; rr < 2; ++rr) {
        const int r = rh * 2 + rr;
        sum[g][rr] = gbuf[tp][0][g][ct_e][quad * 4 + r][l15] + gbuf[tp][1][g][ct_e][quad * 4 + r][l15] +
                     gbuf[tp][2][g][ct_e][quad * 4 + r][l15] + gbuf[tp][3][g][ct_e][quad * 4 + r][l15];
      }
    // (e) epilogue: 2 h-values per thread, all 4 waves participate
#pragma unroll
    for (int rr = 0; rr < 2; ++rr) {
      const int r = rh * 2 + rr;
      float gi = sum[0][rr] + bs[0];
      float gg = sum[1][rr] + bs[1];
      float go = sum[2][rr] + bs[2];
      float cv = sigmoid_f(gi) * tanh_f(gg);
      float hN = sigmoid_f(go) * tanh_f(cv);
      const int row = b0 + quad * 4 + r;
      const int col = j0 + ct_e * 16 + l15;
      if (t == SS - 1) out[(size_t)row * 1024 + col] = hN;
      else hbuf[(size_t)(t + 1) * 131072 + (size_t)row * 1024 + col] = (__fp16)hN;
    }
    // (f) release: per-wave drain into the XCD L2, block barrier, then ONE agent
    //     fetch_add on this block's quarter line of (bg, t+1).
    if (t < SS - 1) {
      asm volatile("s_waitcnt vmcnt(0)" ::: "memory");
      __syncthreads();
      if (tid == 0)
        __hip_atomic_fetch_add(myflag0 + (t + 1) * 64, 1,
                               __ATOMIC_RELAXED, __HIP_MEMORY_SCOPE_AGENT);
    }
  }
}

extern "C" void kernel_launch(void* const* d_in, const int* in_sizes, int n_in,
                              void* d_out, int out_size, void* d_ws, size_t ws_size,
                              hipStream_t stream) {
  const int*   tok  = (const int*)d_in[0];
  const float* emb  = (const float*)d_in[1];
  const float* W_ih = (const float*)d_in[2];
  const float* W_hh = (const float*)d_in[3];
  const float* b_ih = (const float*)d_in[4];
  const float* b_hh = (const float*)d_in[5];
  float* out = (float*)d_out;
  char* ws = (char*)d_ws;

  // ws layout (bytes), total 110,637,056 (~106 MB)
  __fp16* X     = (__fp16*)(ws + 0);              // 33,554,432
  __fp16* Wi3   = (__fp16*)(ws + 33554432);       //  3,145,728
  __fp16* Wh3   = (__fp16*)(ws + 36700160);       //  6,291,456
  float*  bias3 = (float*) (ws + 42991616);       //     12,288
  int*    cnt   = (int*)   (ws + 43003904);       //    524,288 (8 grp x 256 t x 4 lines x 64B)
  __fp16* hbuf  = (__fp16*)(ws + 43528192);       // 67,108,864 (256 step buffers)

  (void)hipMemsetAsync(cnt, 0, 524288, stream);
  (void)hipMemsetAsync(hbuf, 0, 131072 * 2, stream);  // h_0 = 0

  prep_kernel<<<3072, 256, 0, stream>>>(W_ih, W_hh, b_ih, b_hh, Wi3, Wh3, bias3);
  gather_kernel<<<32768, 64, 0, stream>>>(tok, emb, X);
  recur_kernel<<<256, 256, 0, stream>>>(Wh3, Wi3, X, bias3, hbuf, cnt, out);
}